// Round 9
// baseline (42.223 us; speedup 1.0000x reference)
//
#include <hip/hip_runtime.h>

typedef float v2f __attribute__((ext_vector_type(2)));

namespace {
constexpr int kB = 16384;
constexpr int kC = 1000;
constexpr int kNElem = kB * kC;           // 16,384,000
constexpr int kNV8 = kNElem / 8;          // 2,048,000 (8-float chunks)
constexpr int kV8PerRow = kC / 8;         // 125
constexpr int kBlocks = 2048;             // 8 blk/CU = 32 waves/CU (occupancy cap)
                                          // <=4 iters -> <=32 elems/thread (6-bit fields safe)
constexpr int kThreads = 256;
constexpr int kStride = kBlocks * kThreads;  // 524,288
}

// ws: float pf[10][kBlocks]  — per-block hinge-sum partials acc_j (c_0 = 0 -> T)
//     u32   pu[10][kBlocks]  — per-block bin-count partials N_k
// NO global atomics (R8 lesson: ~25K same-line atomic RMWs cost ~20 us of drain).
// finalize (f64): cnt_j = sum_{k>=j} N_k; cum_j = acc_j - c_j*(N - cnt_j);
//                 S_k = cum_k - cum_{k+1}; loss = (1/n) sum_{N_k>0} S_k/N_k.

__device__ __forceinline__ void ghmc_elem(float L, float& bce, unsigned& bin)
{
    const float kLn2   = 0.6931471805599453f;
    const float kNRLn2 = -1.4426950408889634f;
    const float en  = __builtin_amdgcn_exp2f(kNRLn2 * fabsf(L));  // e^{-|L|}
    const float den = 1.f + en;
    const float lg  = __builtin_amdgcn_logf(den);                 // log2(den)
    const float r   = __builtin_amdgcn_rcpf(den);
    bce = fmaf(lg, kLn2, fmaxf(L, 0.f));                          // softplus(L)
    unsigned babs = (unsigned)(10.f * r);
    babs = babs > 9u ? 9u : babs;                                 // in [5,9]
    bin = (L >= 0.f) ? babs : 9u - babs;
}

__device__ __forceinline__ void proc4(const float4 v,
    v2f& a01, v2f& a23, v2f& a45, v2f& a67, v2f& a89,
    unsigned long long& hcnt,
    const v2f C01, const v2f C23, const v2f C45, const v2f C67, const v2f C89)
{
    const float lv[4] = {v.x, v.y, v.z, v.w};
    #pragma unroll
    for (int e = 0; e < 4; ++e) {
        float bce; unsigned bin;
        ghmc_elem(lv[e], bce, bin);
        hcnt += 1ull << (6u * bin);
        const v2f b2 = {bce, bce};
        a01 += __builtin_elementwise_max(b2, C01);
        a23 += __builtin_elementwise_max(b2, C23);
        a45 += __builtin_elementwise_max(b2, C45);
        a67 += __builtin_elementwise_max(b2, C67);
        a89 += __builtin_elementwise_max(b2, C89);
    }
}

__global__ __launch_bounds__(kThreads) void ghmc_main(
    const float* __restrict__ logits,
    const int* __restrict__ tgt,
    float* __restrict__ pf,
    unsigned* __restrict__ pu)
{
    const v2f C01 = {0.0f,        0.10536052f};
    const v2f C23 = {0.22314355f, 0.35667494f};
    const v2f C45 = {0.51082562f, 0.69314718f};
    const v2f C67 = {0.91629073f, 1.20397280f};
    const v2f C89 = {1.60943791f, 2.30258509f};

    v2f a01 = {0.f,0.f}, a23 = {0.f,0.f}, a45 = {0.f,0.f},
        a67 = {0.f,0.f}, a89 = {0.f,0.f};
    unsigned long long hcnt = 0ull;

    const int gid = blockIdx.x * blockDim.x + threadIdx.x;
    const int n = (kNV8 - 1 - gid) / kStride + 1;   // 3 or 4 iterations
    const float4* __restrict__ Lp = reinterpret_cast<const float4*>(logits);

    // depth-2 software pipeline, clamped prefetch addresses (over-load harmless)
    int i = gid;
    int ib = i + kStride;     if (ib >= kNV8) ib = kNV8 - 1;
    float4 a0 = Lp[2 * i],  a1 = Lp[2 * i + 1];
    float4 b0 = Lp[2 * ib], b1 = Lp[2 * ib + 1];

    for (int k = 0; k < n; ++k) {
        // tgt load FIRST: reading it later then needs only vmcnt(2), so the
        // c0/c1 prefetches below are NOT drained (vmcnt completes in order).
        const int row = i / kV8PerRow;                         // magic-mul div
        const int dt  = tgt[row] - (i - row * kV8PerRow) * 8;

        int ic = i + 2 * kStride; if (ic >= kNV8) ic = kNV8 - 1;
        const float4 c0 = Lp[2 * ic], c1 = Lp[2 * ic + 1];

        proc4(a0, a01, a23, a45, a67, a89, hcnt, C01, C23, C45, C67, C89);
        proc4(a1, a01, a23, a45, a67, a89, hcnt, C01, C23, C45, C67, C89);

        // rare correction: this 8-chunk holds the row's target element
        if (__builtin_expect((unsigned)dt < 8u, 0)) {
            float L = a0.x;
            L = (dt == 1) ? a0.y : L;
            L = (dt == 2) ? a0.z : L;
            L = (dt == 3) ? a0.w : L;
            L = (dt == 4) ? a1.x : L;
            L = (dt == 5) ? a1.y : L;
            L = (dt == 6) ? a1.z : L;
            L = (dt == 7) ? a1.w : L;
            float bn_; unsigned bnb;
            ghmc_elem(L, bn_, bnb);            // what the main path added
            const float bt_ = bn_ - L;         // softplus(-L) = softplus(L) - L
            unsigned babs = (bnb >= 5u) ? bnb : 9u - bnb;   // |L|-bin in [5,9]
            const unsigned btb = (L <= 0.f) ? babs : 9u - babs;
            hcnt += (1ull << (6u * btb)) - (1ull << (6u * bnb));
            const v2f bn2 = {bn_, bn_}, bt2 = {bt_, bt_};
            a01 += __builtin_elementwise_max(bt2, C01) - __builtin_elementwise_max(bn2, C01);
            a23 += __builtin_elementwise_max(bt2, C23) - __builtin_elementwise_max(bn2, C23);
            a45 += __builtin_elementwise_max(bt2, C45) - __builtin_elementwise_max(bn2, C45);
            a67 += __builtin_elementwise_max(bt2, C67) - __builtin_elementwise_max(bn2, C67);
            a89 += __builtin_elementwise_max(bt2, C89) - __builtin_elementwise_max(bn2, C89);
        }

        a0 = b0; a1 = b1; b0 = c0; b1 = c1;
        i += kStride;
    }

    // expand 6-bit fields -> two u64 with 12-bit fields (wave sum <= 32*64 = 2048 < 4096)
    unsigned long long lo = 0ull, hi = 0ull;
    #pragma unroll
    for (int k = 0; k < 5; ++k) {
        lo += ((hcnt >> (6 * k))       & 63ull) << (12 * k);
        hi += ((hcnt >> (6 * (k + 5))) & 63ull) << (12 * k);
    }
    float r10[10] = {a01.x, a01.y, a23.x, a23.y, a45.x, a45.y, a67.x, a67.y, a89.x, a89.y};
    #pragma unroll
    for (int off = 32; off > 0; off >>= 1) {
        #pragma unroll
        for (int k = 0; k < 10; ++k) r10[k] += __shfl_down(r10[k], off);
        lo += __shfl_down(lo, off);
        hi += __shfl_down(hi, off);
    }

    __shared__ float              sf[4][10];
    __shared__ unsigned long long sc[4][2];
    const int wave = threadIdx.x >> 6;
    const int lane = threadIdx.x & 63;
    if (lane == 0) {
        #pragma unroll
        for (int k = 0; k < 10; ++k) sf[wave][k] = r10[k];
        sc[wave][0] = lo; sc[wave][1] = hi;
    }
    __syncthreads();
    // per-block partials: PLAIN STORES to a private column — zero global atomics
    const int t = threadIdx.x;
    if (t < 10) {
        pf[t * kBlocks + blockIdx.x] = sf[0][t] + sf[1][t] + sf[2][t] + sf[3][t];
    } else if (t < 20) {
        const int b = t - 10;
        const int half = (b < 5) ? 0 : 1;
        const int sh = 12 * (b < 5 ? b : b - 5);
        unsigned s = 0;
        #pragma unroll
        for (int w = 0; w < 4; ++w) s += (unsigned)((sc[w][half] >> sh) & 4095ull);
        pu[b * kBlocks + blockIdx.x] = s;
    }
}

// 10 waves: wave w reduces sum-slot w (f64) and count-slot w (u32), then finalize.
__global__ __launch_bounds__(640) void ghmc_reduce(
    const float* __restrict__ pf,
    const unsigned* __restrict__ pu,
    float* __restrict__ out)
{
    const int wave = threadIdx.x >> 6;
    const int lane = threadIdx.x & 63;

    double   fs = 0.0;
    unsigned cs = 0u;
    for (int b = lane; b < kBlocks; b += 64) {      // coalesced column reads
        fs += (double)pf[wave * kBlocks + b];
        cs += pu[wave * kBlocks + b];
    }
    #pragma unroll
    for (int off = 32; off > 0; off >>= 1) {
        fs += __shfl_down(fs, off);
        cs += __shfl_down(cs, off);
    }

    __shared__ double   sF[10];
    __shared__ unsigned sC[10];
    if (lane == 0) { sF[wave] = fs; sC[wave] = cs; }
    __syncthreads();

    if (threadIdx.x == 0) {
        const double cj[10] = {0.0,
            0.10536051565782630, 0.22314355131420976, 0.35667494393873245,
            0.51082562376599072, 0.69314718055994531, 0.91629073187415511,
            1.20397280432593600, 1.60943791243410040, 2.30258509299404570};
        double N[10], cnt[11], cum[11];
        for (int k = 0; k < 10; ++k) N[k] = (double)sC[k];
        cnt[10] = 0.0;
        for (int j = 9; j >= 0; --j) cnt[j] = cnt[j + 1] + N[j];
        cum[10] = 0.0;
        cum[0] = sF[0];                                   // T (c=0 hinge is exact)
        for (int j = 1; j <= 9; ++j)
            cum[j] = sF[j] - cj[j] * ((double)kNElem - cnt[j]);
        double loss = 0.0, n = 0.0;
        for (int k = 0; k < 10; ++k) {
            if (N[k] > 0.0) { n += 1.0; loss += (cum[k] - cum[k + 1]) / N[k]; }
        }
        out[0] = (float)(loss / (n > 1.0 ? n : 1.0));
    }
}

extern "C" void kernel_launch(void* const* d_in, const int* in_sizes, int n_in,
                              void* d_out, int out_size, void* d_ws, size_t ws_size,
                              hipStream_t stream)
{
    const float* logits = (const float*)d_in[0];
    const int*   tgt    = (const int*)d_in[1];
    float*    pf = (float*)d_ws;                                   // 10 x 2048 f32
    unsigned* pu = (unsigned*)((char*)d_ws + 10 * kBlocks * 4);    // 10 x 2048 u32
    ghmc_main<<<kBlocks, kThreads, 0, stream>>>(logits, tgt, pf, pu);
    ghmc_reduce<<<1, 640, 0, stream>>>(pf, pu, (float*)d_out);
}

// Round 10
// 31.815 us; speedup vs baseline: 1.3271x; 1.3271x over previous
//
#include <hip/hip_runtime.h>

typedef float v2f __attribute__((ext_vector_type(2)));

namespace {
constexpr int kB = 16384;
constexpr int kC = 1000;
constexpr int kNElem = kB * kC;           // 16,384,000
constexpr int kNV4 = kNElem / 4;          // 4,096,000 float4 chunks
constexpr int kV4PerRow = kC / 4;         // 250
constexpr int kBlocks = 1280;             // n = 12..13 iters -> <=52 elems/thread (6-bit safe)
constexpr int kThreads = 256;
constexpr int kS = kBlocks * kThreads;    // 327,680 (grid stride in float4s)
}

// ws: float pf[10][kBlocks] — per-block hinge-sum partials acc_j (c_0 = 0 -> T)
//     u32   pu[10][kBlocks] — per-block bin-count partials N_k
// No global atomics (R8 lesson). finalize (f64): cnt_j = sum_{k>=j} N_k;
// cum_j = acc_j - c_j*(N - cnt_j); S_k = cum_k - cum_{k+1};
// loss = (1/n) sum_{N_k>0} S_k/N_k.

__device__ __forceinline__ void ghmc_elem(float L, float& bce, unsigned& bin)
{
    const float kLn2   = 0.6931471805599453f;
    const float kNRLn2 = -1.4426950408889634f;
    const float en  = __builtin_amdgcn_exp2f(kNRLn2 * fabsf(L));  // e^{-|L|}
    const float den = 1.f + en;
    const float lg  = __builtin_amdgcn_logf(den);                 // log2(den)
    const float r   = __builtin_amdgcn_rcpf(den);
    bce = fmaf(lg, kLn2, fmaxf(L, 0.f));                          // softplus(L)
    unsigned babs = (unsigned)(10.f * r);
    babs = babs > 9u ? 9u : babs;                                 // in [5,9]
    bin = (L >= 0.f) ? babs : 9u - babs;
}

// process one float4 chunk (4 consecutive elements of one row) + its rare
// target correction. dt = target col - 4*chunk_col (correction iff 0<=dt<4).
__device__ __forceinline__ void proc4(const float4 v, int dt,
    v2f& a01, v2f& a23, v2f& a45, v2f& a67, v2f& a89,
    unsigned long long& hcnt,
    const v2f C01, const v2f C23, const v2f C45, const v2f C67, const v2f C89)
{
    const float lv[4] = {v.x, v.y, v.z, v.w};
    #pragma unroll
    for (int e = 0; e < 4; ++e) {
        float bce; unsigned bin;
        ghmc_elem(lv[e], bce, bin);
        hcnt += 1ull << (6u * bin);
        const v2f b2 = {bce, bce};
        a01 += __builtin_elementwise_max(b2, C01);
        a23 += __builtin_elementwise_max(b2, C23);
        a45 += __builtin_elementwise_max(b2, C45);
        a67 += __builtin_elementwise_max(b2, C67);
        a89 += __builtin_elementwise_max(b2, C89);
    }
    if (__builtin_expect((unsigned)dt < 4u, 0)) {
        float L = v.x;
        L = (dt == 1) ? v.y : L;
        L = (dt == 2) ? v.z : L;
        L = (dt == 3) ? v.w : L;
        float bn_; unsigned bnb;
        ghmc_elem(L, bn_, bnb);                 // what the main path added
        const float bt_ = bn_ - L;              // softplus(-L) = softplus(L) - L
        const unsigned babs = (bnb >= 5u) ? bnb : 9u - bnb;   // |L|-bin in [5,9]
        const unsigned btb  = (L <= 0.f) ? babs : 9u - babs;
        hcnt += (1ull << (6u * btb)) - (1ull << (6u * bnb));
        const v2f bn2 = {bn_, bn_}, bt2 = {bt_, bt_};
        a01 += __builtin_elementwise_max(bt2, C01) - __builtin_elementwise_max(bn2, C01);
        a23 += __builtin_elementwise_max(bt2, C23) - __builtin_elementwise_max(bn2, C23);
        a45 += __builtin_elementwise_max(bt2, C45) - __builtin_elementwise_max(bn2, C45);
        a67 += __builtin_elementwise_max(bt2, C67) - __builtin_elementwise_max(bn2, C67);
        a89 += __builtin_elementwise_max(bt2, C89) - __builtin_elementwise_max(bn2, C89);
    }
}

__device__ __forceinline__ int dt_for(const int* __restrict__ tgt, int i)
{
    const int row = i / kV4PerRow;                 // magic-mul div (const 250)
    return tgt[row] - (i - row * kV4PerRow) * 4;   // tgt is L1/L2-resident (64 KB)
}

__global__ __launch_bounds__(kThreads) void ghmc_main(
    const float* __restrict__ logits,
    const int* __restrict__ tgt,
    float* __restrict__ pf,
    unsigned* __restrict__ pu)
{
    const v2f C01 = {0.0f,        0.10536052f};
    const v2f C23 = {0.22314355f, 0.35667494f};
    const v2f C45 = {0.51082562f, 0.69314718f};
    const v2f C67 = {0.91629073f, 1.20397280f};
    const v2f C89 = {1.60943791f, 2.30258509f};

    v2f a01 = {0.f,0.f}, a23 = {0.f,0.f}, a45 = {0.f,0.f},
        a67 = {0.f,0.f}, a89 = {0.f,0.f};
    unsigned long long hcnt = 0ull;

    const int gid = blockIdx.x * blockDim.x + threadIdx.x;
    const int n = (kNV4 - 1 - gid) / kS + 1;      // 12 or 13 iterations
    const float4* __restrict__ Lp = reinterpret_cast<const float4*>(logits);

    auto ld = [&](int idx) {                      // clamped (over-read harmless)
        idx = idx < kNV4 ? idx : kNV4 - 1;
        return Lp[idx];
    };

    // modulo-scheduled software pipeline, depth 3, unroll-by-4:
    // four NAMED registers used cyclically -> no rotation copies -> no
    // per-iteration vmcnt(0) drain (each load has 3 iters before its use).
    int i = gid;
    float4 q0 = ld(i), q1 = ld(i + kS), q2 = ld(i + 2 * kS);

    int k = 0;
    for (; k + 4 <= n; k += 4) {
        float4 q3 = ld(i + 3 * kS);
        proc4(q0, dt_for(tgt, i),          a01, a23, a45, a67, a89, hcnt, C01, C23, C45, C67, C89);
        q0 = ld(i + 4 * kS);
        proc4(q1, dt_for(tgt, i + kS),     a01, a23, a45, a67, a89, hcnt, C01, C23, C45, C67, C89);
        q1 = ld(i + 5 * kS);
        proc4(q2, dt_for(tgt, i + 2 * kS), a01, a23, a45, a67, a89, hcnt, C01, C23, C45, C67, C89);
        q2 = ld(i + 6 * kS);
        proc4(q3, dt_for(tgt, i + 3 * kS), a01, a23, a45, a67, a89, hcnt, C01, C23, C45, C67, C89);
        i += 4 * kS;
    }
    for (; k < n; ++k) {                          // tail: 0 or 1 iteration
        proc4(q0, dt_for(tgt, i), a01, a23, a45, a67, a89, hcnt, C01, C23, C45, C67, C89);
        q0 = q1; q1 = q2;
        i += kS;
    }

    // expand 6-bit fields -> two u64 with 12-bit fields (wave sum <= 52*64 = 3328 < 4096)
    unsigned long long lo = 0ull, hi = 0ull;
    #pragma unroll
    for (int j = 0; j < 5; ++j) {
        lo += ((hcnt >> (6 * j))       & 63ull) << (12 * j);
        hi += ((hcnt >> (6 * (j + 5))) & 63ull) << (12 * j);
    }
    float r10[10] = {a01.x, a01.y, a23.x, a23.y, a45.x, a45.y, a67.x, a67.y, a89.x, a89.y};
    #pragma unroll
    for (int off = 32; off > 0; off >>= 1) {
        #pragma unroll
        for (int j = 0; j < 10; ++j) r10[j] += __shfl_down(r10[j], off);
        lo += __shfl_down(lo, off);
        hi += __shfl_down(hi, off);
    }

    __shared__ float              sf[4][10];
    __shared__ unsigned long long sc[4][2];
    const int wave = threadIdx.x >> 6;
    const int lane = threadIdx.x & 63;
    if (lane == 0) {
        #pragma unroll
        for (int j = 0; j < 10; ++j) sf[wave][j] = r10[j];
        sc[wave][0] = lo; sc[wave][1] = hi;
    }
    __syncthreads();
    // per-block partials: PLAIN STORES to a private column — zero global atomics
    const int t = threadIdx.x;
    if (t < 10) {
        pf[t * kBlocks + blockIdx.x] = sf[0][t] + sf[1][t] + sf[2][t] + sf[3][t];
    } else if (t < 20) {
        const int b = t - 10;
        const int half = (b < 5) ? 0 : 1;
        const int sh = 12 * (b < 5 ? b : b - 5);
        unsigned s = 0;
        #pragma unroll
        for (int w = 0; w < 4; ++w) s += (unsigned)((sc[w][half] >> sh) & 4095ull);
        pu[b * kBlocks + blockIdx.x] = s;
    }
}

// 10 waves: wave w reduces sum-slot w (f64) and count-slot w (u32), vectorized.
__global__ __launch_bounds__(640) void ghmc_reduce(
    const float* __restrict__ pf,
    const unsigned* __restrict__ pu,
    float* __restrict__ out)
{
    const int wave = threadIdx.x >> 6;
    const int lane = threadIdx.x & 63;

    const float4* pf4 = reinterpret_cast<const float4*>(pf + wave * kBlocks);
    const uint4*  pu4 = reinterpret_cast<const uint4*>(pu + wave * kBlocks);
    double   fs = 0.0;
    unsigned cs = 0u;
    #pragma unroll
    for (int it = 0; it < kBlocks / 256; ++it) {   // 5 float4/uint4 loads per lane
        const float4 f = pf4[lane + it * 64];
        const uint4  u = pu4[lane + it * 64];
        fs += (double)f.x + (double)f.y + (double)f.z + (double)f.w;
        cs += u.x + u.y + u.z + u.w;
    }
    #pragma unroll
    for (int off = 32; off > 0; off >>= 1) {
        fs += __shfl_down(fs, off);
        cs += __shfl_down(cs, off);
    }

    __shared__ double   sF[10];
    __shared__ unsigned sC[10];
    if (lane == 0) { sF[wave] = fs; sC[wave] = cs; }
    __syncthreads();

    if (threadIdx.x == 0) {
        const double cj[10] = {0.0,
            0.10536051565782630, 0.22314355131420976, 0.35667494393873245,
            0.51082562376599072, 0.69314718055994531, 0.91629073187415511,
            1.20397280432593600, 1.60943791243410040, 2.30258509299404570};
        double N[10], cnt[11], cum[11];
        for (int j = 0; j < 10; ++j) N[j] = (double)sC[j];
        cnt[10] = 0.0;
        for (int j = 9; j >= 0; --j) cnt[j] = cnt[j + 1] + N[j];
        cum[10] = 0.0;
        cum[0] = sF[0];                                   // T (c=0 hinge is exact)
        for (int j = 1; j <= 9; ++j)
            cum[j] = sF[j] - cj[j] * ((double)kNElem - cnt[j]);
        double loss = 0.0, n = 0.0;
        for (int j = 0; j < 10; ++j) {
            if (N[j] > 0.0) { n += 1.0; loss += (cum[j] - cum[j + 1]) / N[j]; }
        }
        out[0] = (float)(loss / (n > 1.0 ? n : 1.0));
    }
}

extern "C" void kernel_launch(void* const* d_in, const int* in_sizes, int n_in,
                              void* d_out, int out_size, void* d_ws, size_t ws_size,
                              hipStream_t stream)
{
    const float* logits = (const float*)d_in[0];
    const int*   tgt    = (const int*)d_in[1];
    float*    pf = (float*)d_ws;                                   // 10 x 1280 f32
    unsigned* pu = (unsigned*)((char*)d_ws + 10 * kBlocks * 4);    // 10 x 1280 u32
    ghmc_main<<<kBlocks, kThreads, 0, stream>>>(logits, tgt, pf, pu);
    ghmc_reduce<<<1, 640, 0, stream>>>(pf, pu, (float*)d_out);
}